// Round 1
// baseline (217.511 us; speedup 1.0000x reference)
//
#include <hip/hip_runtime.h>
#include <math.h>

// Problem constants (from reference): z [4,32,32,32] f32, embedding [32768,32] f32.
constexpr int Bc  = 4;
constexpr int Dc  = 32;
constexpr int Hc  = 32;
constexpr int Wc  = 32;
constexpr int NE  = 32768;
constexpr int HWc = Hc * Wc;        // 1024
constexpr int POS = Bc * HWc;       // 4096 positions
constexpr int PPB = 256;            // positions per block (4 waves, lane = position)

// Kernel 1: each thread owns one spatial position (z vector in 32 VGPRs) and scans
// a chunk of codes. Code addresses are wave-uniform -> scalar loads (SGPR broadcast),
// so the inner loop is pure v_fma_f32 with an SGPR operand. 2 codes/iter breaks the
// accumulator dependency chain.
__global__ __launch_bounds__(256) void vq_partial_kernel(
    const float* __restrict__ z, const float* __restrict__ emb,
    float* __restrict__ pval, int* __restrict__ pidx, int codesPerChunk)
{
    const int p     = blockIdx.x * PPB + threadIdx.x;   // 0..4095
    const int chunk = blockIdx.y;
    const int b  = p >> 10;          // / 1024
    const int hw = p & (HWc - 1);    // % 1024

    // z[b][d][h][w] -> stride HWc over d; lanes (consecutive hw) coalesce per d.
    const float* zp = z + (size_t)b * Dc * HWc + hw;
    float zv[Dc];
#pragma unroll
    for (int d = 0; d < Dc; ++d) zv[d] = zp[(size_t)d * HWc];

    const int c0 = chunk * codesPerChunk;
    float best = -INFINITY;
    int   bidx = c0;

    for (int c = c0; c < c0 + codesPerChunk; c += 2) {
        const float* e = emb + (size_t)c * Dc;   // wave-uniform address
        float a0 = 0.f, a1 = 0.f;
#pragma unroll
        for (int k = 0; k < Dc; ++k) {
            a0 = fmaf(zv[k], e[k],      a0);
            a1 = fmaf(zv[k], e[Dc + k], a1);
        }
        // strict '>' keeps the earliest index on ties (argmax semantics)
        if (a0 > best) { best = a0; bidx = c; }
        if (a1 > best) { best = a1; bidx = c + 1; }
    }

    const int nchunks = gridDim.y;
    pval[(size_t)p * nchunks + chunk] = best;
    pidx[(size_t)p * nchunks + chunk] = bidx;
}

// Kernel 2: reduce partial argmax per position (ascending chunk order == ascending
// code index, strict '>' preserves first-max tie-break), gather embedding row,
// write z_q [b,d,h,w] (coalesced across lanes per d) and indices as float.
__global__ __launch_bounds__(256) void vq_reduce_kernel(
    const float* __restrict__ pval, const int* __restrict__ pidx,
    const float* __restrict__ emb, float* __restrict__ zq,
    float* __restrict__ indOut, int nchunks)
{
    const int p = blockIdx.x * 256 + threadIdx.x;
    float best = -INFINITY;
    int   bidx = 0;
    for (int c = 0; c < nchunks; ++c) {
        float v = pval[(size_t)p * nchunks + c];
        if (v > best) { best = v; bidx = pidx[(size_t)p * nchunks + c]; }
    }

    const int b  = p >> 10;
    const int hw = p & (HWc - 1);
    const float* e = emb + (size_t)bidx * Dc;
    float* o = zq + (size_t)b * Dc * HWc + hw;
#pragma unroll
    for (int d = 0; d < Dc; ++d) o[(size_t)d * HWc] = e[d];

    indOut[p] = (float)bidx;   // indices <= 32767 are exact in fp32
}

extern "C" void kernel_launch(void* const* d_in, const int* in_sizes, int n_in,
                              void* d_out, int out_size, void* d_ws, size_t ws_size,
                              hipStream_t stream)
{
    const float* z   = (const float*)d_in[0];
    const float* emb = (const float*)d_in[1];

    float* out    = (float*)d_out;
    float* zq     = out;                       // 4*32*32*32 = 131072 floats
    float* indOut = out + (size_t)Bc * Dc * HWc; // then 4096 index values (as f32)

    // 64 code-chunks -> 4096 waves (4/SIMD) for latency hiding; clamp to workspace.
    int nchunks = 64;
    while (nchunks > 1 && (size_t)POS * nchunks * 8 > ws_size) nchunks >>= 1;
    const int codesPerChunk = NE / nchunks;

    float* pval = (float*)d_ws;
    int*   pidx = (int*)((char*)d_ws + (size_t)POS * nchunks * sizeof(float));

    dim3 g1(POS / PPB, nchunks);
    hipLaunchKernelGGL(vq_partial_kernel, g1, dim3(256), 0, stream,
                       z, emb, pval, pidx, codesPerChunk);
    hipLaunchKernelGGL(vq_reduce_kernel, dim3(POS / 256), dim3(256), 0, stream,
                       pval, pidx, emb, zq, indOut, nchunks);
}

// Round 2
// 194.646 us; speedup vs baseline: 1.1175x; 1.1175x over previous
//
#include <hip/hip_runtime.h>
#include <math.h>

// Problem constants: z [4,32,32,32] f32, embedding [32768,32] f32.
constexpr int Bc  = 4;
constexpr int Dc  = 32;
constexpr int Hc  = 32;
constexpr int Wc  = 32;
constexpr int NE  = 32768;
constexpr int HWc = Hc * Wc;        // 1024
constexpr int POS = Bc * HWc;       // 4096 positions
constexpr int PPB = 256;            // positions per block (4 waves, lane = position)

// Kernel 1: one thread per spatial position; z vector PINNED in 32 VGPRs
// (asm barrier prevents the compiler from sinking the loads into the loop,
// which is what capped round-1 at VGPR=28 / 40 TF). Code-vector addresses are
// wave-uniform -> s_load_dwordx16 into SGPRs (scalar pipe), so the inner loop
// issues almost pure v_fma_f32. 2 codes/iter = 2 independent FMA chains.
__global__ __launch_bounds__(256) void vq_partial_kernel(
    const float* __restrict__ z, const float* __restrict__ emb,
    float* __restrict__ pval, int* __restrict__ pidx, int codesPerChunk)
{
    const int p     = blockIdx.x * PPB + threadIdx.x;   // 0..4095
    const int chunk = blockIdx.y;
    const int b  = p >> 10;          // / 1024
    const int hw = p & (HWc - 1);    // % 1024

    // z[b][d][h][w]: stride HWc over d; lanes (consecutive hw) coalesce per d.
    const float* zp = z + (size_t)b * Dc * HWc + hw;
    float zv[Dc];
#pragma unroll
    for (int d = 0; d < Dc; ++d) zv[d] = zp[(size_t)d * HWc];
    // Pin each element to a VGPR: opaque to the optimizer, cannot be
    // rematerialized by re-loading from memory inside the loop.
#pragma unroll
    for (int d = 0; d < Dc; ++d) asm volatile("" : "+v"(zv[d]));

    const int c0 = chunk * codesPerChunk;
    const float* e = emb + (size_t)c0 * Dc;   // wave-uniform address
    float best = -INFINITY;
    int   bidx = c0;

    const int iters = codesPerChunk >> 1;
    int c = c0;
    for (int it = 0; it < iters; ++it, c += 2, e += 2 * Dc) {
        float a0 = 0.f, a1 = 0.f;
#pragma unroll
        for (int k = 0; k < Dc; ++k) {
            a0 = fmaf(zv[k], e[k],      a0);
            a1 = fmaf(zv[k], e[Dc + k], a1);
        }
        // strict '>' keeps the earliest index on ties (argmax semantics)
        if (a0 > best) { best = a0; bidx = c; }
        if (a1 > best) { best = a1; bidx = c + 1; }
    }

    // chunk-major so kernel 2's reads coalesce
    pval[(size_t)chunk * POS + p] = best;
    pidx[(size_t)chunk * POS + p] = bidx;
}

// Kernel 2: reduce partial argmax per position (ascending chunk order ==
// ascending code index, strict '>' preserves first-max tie-break), gather the
// winning embedding row, write z_q [b,d,h,w] coalesced, indices as float.
__global__ __launch_bounds__(256) void vq_reduce_kernel(
    const float* __restrict__ pval, const int* __restrict__ pidx,
    const float* __restrict__ emb, float* __restrict__ zq,
    float* __restrict__ indOut, int nchunks)
{
    const int p = blockIdx.x * 256 + threadIdx.x;
    float best = -INFINITY;
    int   bidx = 0;
#pragma unroll 8
    for (int c = 0; c < nchunks; ++c) {
        float v = pval[(size_t)c * POS + p];
        int  id = pidx[(size_t)c * POS + p];
        if (v > best) { best = v; bidx = id; }
    }

    const int b  = p >> 10;
    const int hw = p & (HWc - 1);
    const float* e = emb + (size_t)bidx * Dc;
    float* o = zq + (size_t)b * Dc * HWc + hw;
#pragma unroll
    for (int d = 0; d < Dc; ++d) o[(size_t)d * HWc] = e[d];

    indOut[p] = (float)bidx;   // indices <= 32767 are exact in fp32
}

extern "C" void kernel_launch(void* const* d_in, const int* in_sizes, int n_in,
                              void* d_out, int out_size, void* d_ws, size_t ws_size,
                              hipStream_t stream)
{
    const float* z   = (const float*)d_in[0];
    const float* emb = (const float*)d_in[1];

    float* out    = (float*)d_out;
    float* zq     = out;                         // 131072 floats
    float* indOut = out + (size_t)Bc * Dc * HWc; // 4096 index values (as f32)

    // 128 chunks -> 2048 blocks = 8 blocks/CU = 32 waves/CU for latency hiding.
    int nchunks = 128;
    while (nchunks > 1 && (size_t)POS * nchunks * 8 > ws_size) nchunks >>= 1;
    const int codesPerChunk = NE / nchunks;

    float* pval = (float*)d_ws;
    int*   pidx = (int*)((char*)d_ws + (size_t)POS * nchunks * sizeof(float));

    dim3 g1(POS / PPB, nchunks);
    hipLaunchKernelGGL(vq_partial_kernel, g1, dim3(256), 0, stream,
                       z, emb, pval, pidx, codesPerChunk);
    hipLaunchKernelGGL(vq_reduce_kernel, dim3(POS / 256), dim3(256), 0, stream,
                       pval, pidx, emb, zq, indOut, nchunks);
}

// Round 3
// 144.952 us; speedup vs baseline: 1.5006x; 1.3428x over previous
//
#include <hip/hip_runtime.h>
#include <math.h>

// Problem constants: z [4,32,32,32] f32, embedding [32768,32] f32.
constexpr int Bc  = 4;
constexpr int Dc  = 32;
constexpr int HWc = 1024;           // 32*32
constexpr int NE  = 32768;
constexpr int POS = Bc * HWc;       // 4096 positions
constexpr int HALF = POS / 2;       // 2048: thread t owns positions t and t+2048

// Kernel 1: each thread owns TWO positions (64 z-floats pinned in VGPRs) and
// scans a chunk of codes, 2 codes per iteration. Embedding operands are read
// as float4 at wave-uniform addresses with constant offsets (scalarizes or
// folds to offset: immediates). 4 independent FMA chains (2 codes x 2 pos).
// __launch_bounds__(256,4) caps VGPRs at 128 -> 4 waves/SIMD resident (the
// round-2 kernel allocated ~192 regs -> 2 waves/SIMD -> 29% idle).
__global__ __launch_bounds__(256, 4) void vq_partial_kernel(
    const float* __restrict__ z, const float* __restrict__ emb,
    float* __restrict__ pval, int* __restrict__ pidx, int codesPerChunk)
{
    const int t     = blockIdx.x * 256 + threadIdx.x;   // 0..2047
    const int chunk = blockIdx.y;
    const int p0 = t;
    const int p1 = t + HALF;

    const int b0 = p0 >> 10, hw0 = p0 & (HWc - 1);
    const int b1 = p1 >> 10, hw1 = p1 & (HWc - 1);
    const float* zp0 = z + (size_t)b0 * Dc * HWc + hw0;
    const float* zp1 = z + (size_t)b1 * Dc * HWc + hw1;

    float za[Dc], zb[Dc];
#pragma unroll
    for (int d = 0; d < Dc; ++d) {
        za[d] = zp0[(size_t)d * HWc];
        zb[d] = zp1[(size_t)d * HWc];
    }
#pragma unroll
    for (int d = 0; d < Dc; ++d) asm volatile("" : "+v"(za[d]), "+v"(zb[d]));

    const int c0 = chunk * codesPerChunk;
    const float4* e4 = reinterpret_cast<const float4*>(emb + (size_t)c0 * Dc);

    float best0 = -INFINITY, best1 = -INFINITY;
    int   bi0 = c0, bi1 = c0;

    int c = c0;
    const int iters = codesPerChunk >> 1;
#pragma unroll 1
    for (int it = 0; it < iters; ++it, c += 2, e4 += 16) {
        float aC0P0 = 0.f, aC0P1 = 0.f, aC1P0 = 0.f, aC1P1 = 0.f;
#pragma unroll
        for (int q = 0; q < 8; ++q) {
            const float4 ea = e4[q];        // code c,   k = 4q..4q+3
            const float4 eb = e4[8 + q];    // code c+1, k = 4q..4q+3
            aC0P0 = fmaf(za[4*q+0], ea.x, aC0P0);
            aC0P1 = fmaf(zb[4*q+0], ea.x, aC0P1);
            aC1P0 = fmaf(za[4*q+0], eb.x, aC1P0);
            aC1P1 = fmaf(zb[4*q+0], eb.x, aC1P1);
            aC0P0 = fmaf(za[4*q+1], ea.y, aC0P0);
            aC0P1 = fmaf(zb[4*q+1], ea.y, aC0P1);
            aC1P0 = fmaf(za[4*q+1], eb.y, aC1P0);
            aC1P1 = fmaf(zb[4*q+1], eb.y, aC1P1);
            aC0P0 = fmaf(za[4*q+2], ea.z, aC0P0);
            aC0P1 = fmaf(zb[4*q+2], ea.z, aC0P1);
            aC1P0 = fmaf(za[4*q+2], eb.z, aC1P0);
            aC1P1 = fmaf(zb[4*q+2], eb.z, aC1P1);
            aC0P0 = fmaf(za[4*q+3], ea.w, aC0P0);
            aC0P1 = fmaf(zb[4*q+3], ea.w, aC0P1);
            aC1P0 = fmaf(za[4*q+3], eb.w, aC1P0);
            aC1P1 = fmaf(zb[4*q+3], eb.w, aC1P1);
        }
        // strict '>' in ascending code order == first-index tie-break (argmax)
        if (aC0P0 > best0) { best0 = aC0P0; bi0 = c; }
        if (aC1P0 > best0) { best0 = aC1P0; bi0 = c + 1; }
        if (aC0P1 > best1) { best1 = aC0P1; bi1 = c; }
        if (aC1P1 > best1) { best1 = aC1P1; bi1 = c + 1; }
    }

    // chunk-major so kernel 2's reads coalesce
    pval[(size_t)chunk * POS + p0] = best0;
    pidx[(size_t)chunk * POS + p0] = bi0;
    pval[(size_t)chunk * POS + p1] = best1;
    pidx[(size_t)chunk * POS + p1] = bi1;
}

// Kernel 2: reduce partial argmax per position (ascending chunk order ==
// ascending code index, strict '>' preserves first-max tie-break), gather the
// winning embedding row, write z_q [b,d,h,w] coalesced, indices as float.
__global__ __launch_bounds__(256) void vq_reduce_kernel(
    const float* __restrict__ pval, const int* __restrict__ pidx,
    const float* __restrict__ emb, float* __restrict__ zq,
    float* __restrict__ indOut, int nchunks)
{
    const int p = blockIdx.x * 256 + threadIdx.x;
    float best = -INFINITY;
    int   bidx = 0;
#pragma unroll 8
    for (int c = 0; c < nchunks; ++c) {
        float v = pval[(size_t)c * POS + p];
        int  id = pidx[(size_t)c * POS + p];
        if (v > best) { best = v; bidx = id; }
    }

    const int b  = p >> 10;
    const int hw = p & (HWc - 1);
    const float* e = emb + (size_t)bidx * Dc;
    float* o = zq + (size_t)b * Dc * HWc + hw;
#pragma unroll
    for (int d = 0; d < Dc; ++d) o[(size_t)d * HWc] = e[d];

    indOut[p] = (float)bidx;   // indices <= 32767 are exact in fp32
}

extern "C" void kernel_launch(void* const* d_in, const int* in_sizes, int n_in,
                              void* d_out, int out_size, void* d_ws, size_t ws_size,
                              hipStream_t stream)
{
    const float* z   = (const float*)d_in[0];
    const float* emb = (const float*)d_in[1];

    float* out    = (float*)d_out;
    float* zq     = out;                         // 131072 floats
    float* indOut = out + (size_t)Bc * Dc * HWc; // 4096 index values (as f32)

    // 128 chunks: 8x128 = 1024 blocks = 4 blocks/CU = 16 waves/CU resident.
    int nchunks = 128;
    while (nchunks > 1 && (size_t)POS * nchunks * 8 > ws_size) nchunks >>= 1;
    const int codesPerChunk = NE / nchunks;

    float* pval = (float*)d_ws;
    int*   pidx = (int*)((char*)d_ws + (size_t)POS * nchunks * sizeof(float));

    dim3 g1(HALF / 256, nchunks);
    hipLaunchKernelGGL(vq_partial_kernel, g1, dim3(256), 0, stream,
                       z, emb, pval, pidx, codesPerChunk);
    hipLaunchKernelGGL(vq_reduce_kernel, dim3(POS / 256), dim3(256), 0, stream,
                       pval, pidx, emb, zq, indOut, nchunks);
}

// Round 4
// 144.047 us; speedup vs baseline: 1.5100x; 1.0063x over previous
//
#include <hip/hip_runtime.h>
#include <math.h>

// Problem constants: z [4,32,32,32] f32, embedding [32768,32] f32.
constexpr int Bc  = 4;
constexpr int Dc  = 32;
constexpr int HWc = 1024;           // 32*32
constexpr int NE  = 32768;
constexpr int POS = Bc * HWc;       // 4096 positions
constexpr int HALF = POS / 2;       // 2048: thread t owns positions t and t+2048

// Kernel 1: each thread owns TWO positions (64 z-floats pinned in VGPRs) and
// scans a chunk of codes, 2 codes per iteration. Embedding operands are read
// as float4 at wave-uniform addresses with constant offsets (scalarizes or
// folds to offset: immediates). 4 independent FMA chains (2 codes x 2 pos).
// __launch_bounds__(256,4) caps VGPRs at 128 -> 4 waves/SIMD resident (the
// round-2 kernel allocated ~192 regs -> 2 waves/SIMD -> 29% idle).
__global__ __launch_bounds__(256, 4) void vq_partial_kernel(
    const float* __restrict__ z, const float* __restrict__ emb,
    float* __restrict__ pval, int* __restrict__ pidx, int codesPerChunk)
{
    const int t     = blockIdx.x * 256 + threadIdx.x;   // 0..2047
    const int chunk = blockIdx.y;
    const int p0 = t;
    const int p1 = t + HALF;

    const int b0 = p0 >> 10, hw0 = p0 & (HWc - 1);
    const int b1 = p1 >> 10, hw1 = p1 & (HWc - 1);
    const float* zp0 = z + (size_t)b0 * Dc * HWc + hw0;
    const float* zp1 = z + (size_t)b1 * Dc * HWc + hw1;

    float za[Dc], zb[Dc];
#pragma unroll
    for (int d = 0; d < Dc; ++d) {
        za[d] = zp0[(size_t)d * HWc];
        zb[d] = zp1[(size_t)d * HWc];
    }
#pragma unroll
    for (int d = 0; d < Dc; ++d) asm volatile("" : "+v"(za[d]), "+v"(zb[d]));

    const int c0 = chunk * codesPerChunk;
    const float4* e4 = reinterpret_cast<const float4*>(emb + (size_t)c0 * Dc);

    float best0 = -INFINITY, best1 = -INFINITY;
    int   bi0 = c0, bi1 = c0;

    int c = c0;
    const int iters = codesPerChunk >> 1;
#pragma unroll 1
    for (int it = 0; it < iters; ++it, c += 2, e4 += 16) {
        float aC0P0 = 0.f, aC0P1 = 0.f, aC1P0 = 0.f, aC1P1 = 0.f;
#pragma unroll
        for (int q = 0; q < 8; ++q) {
            const float4 ea = e4[q];        // code c,   k = 4q..4q+3
            const float4 eb = e4[8 + q];    // code c+1, k = 4q..4q+3
            aC0P0 = fmaf(za[4*q+0], ea.x, aC0P0);
            aC0P1 = fmaf(zb[4*q+0], ea.x, aC0P1);
            aC1P0 = fmaf(za[4*q+0], eb.x, aC1P0);
            aC1P1 = fmaf(zb[4*q+0], eb.x, aC1P1);
            aC0P0 = fmaf(za[4*q+1], ea.y, aC0P0);
            aC0P1 = fmaf(zb[4*q+1], ea.y, aC0P1);
            aC1P0 = fmaf(za[4*q+1], eb.y, aC1P0);
            aC1P1 = fmaf(zb[4*q+1], eb.y, aC1P1);
            aC0P0 = fmaf(za[4*q+2], ea.z, aC0P0);
            aC0P1 = fmaf(zb[4*q+2], ea.z, aC0P1);
            aC1P0 = fmaf(za[4*q+2], eb.z, aC1P0);
            aC1P1 = fmaf(zb[4*q+2], eb.z, aC1P1);
            aC0P0 = fmaf(za[4*q+3], ea.w, aC0P0);
            aC0P1 = fmaf(zb[4*q+3], ea.w, aC0P1);
            aC1P0 = fmaf(za[4*q+3], eb.w, aC1P0);
            aC1P1 = fmaf(zb[4*q+3], eb.w, aC1P1);
        }
        // strict '>' in ascending code order == first-index tie-break (argmax)
        if (aC0P0 > best0) { best0 = aC0P0; bi0 = c; }
        if (aC1P0 > best0) { best0 = aC1P0; bi0 = c + 1; }
        if (aC0P1 > best1) { best1 = aC0P1; bi1 = c; }
        if (aC1P1 > best1) { best1 = aC1P1; bi1 = c + 1; }
    }

    // chunk-major so kernel 2's reads coalesce
    pval[(size_t)chunk * POS + p0] = best0;
    pidx[(size_t)chunk * POS + p0] = bi0;
    pval[(size_t)chunk * POS + p1] = best1;
    pidx[(size_t)chunk * POS + p1] = bi1;
}

// Kernel 2: reduce partial argmax per position (ascending chunk order ==
// ascending code index, strict '>' preserves first-max tie-break), gather the
// winning embedding row, write z_q [b,d,h,w] coalesced, indices as float.
__global__ __launch_bounds__(256) void vq_reduce_kernel(
    const float* __restrict__ pval, const int* __restrict__ pidx,
    const float* __restrict__ emb, float* __restrict__ zq,
    float* __restrict__ indOut, int nchunks)
{
    const int p = blockIdx.x * 256 + threadIdx.x;
    float best = -INFINITY;
    int   bidx = 0;
#pragma unroll 8
    for (int c = 0; c < nchunks; ++c) {
        float v = pval[(size_t)c * POS + p];
        int  id = pidx[(size_t)c * POS + p];
        if (v > best) { best = v; bidx = id; }
    }

    const int b  = p >> 10;
    const int hw = p & (HWc - 1);
    const float* e = emb + (size_t)bidx * Dc;
    float* o = zq + (size_t)b * Dc * HWc + hw;
#pragma unroll
    for (int d = 0; d < Dc; ++d) o[(size_t)d * HWc] = e[d];

    indOut[p] = (float)bidx;   // indices <= 32767 are exact in fp32
}

extern "C" void kernel_launch(void* const* d_in, const int* in_sizes, int n_in,
                              void* d_out, int out_size, void* d_ws, size_t ws_size,
                              hipStream_t stream)
{
    const float* z   = (const float*)d_in[0];
    const float* emb = (const float*)d_in[1];

    float* out    = (float*)d_out;
    float* zq     = out;                         // 131072 floats
    float* indOut = out + (size_t)Bc * Dc * HWc; // 4096 index values (as f32)

    // 128 chunks: 8x128 = 1024 blocks = 4 blocks/CU = 16 waves/CU resident.
    int nchunks = 128;
    while (nchunks > 1 && (size_t)POS * nchunks * 8 > ws_size) nchunks >>= 1;
    const int codesPerChunk = NE / nchunks;

    float* pval = (float*)d_ws;
    int*   pidx = (int*)((char*)d_ws + (size_t)POS * nchunks * sizeof(float));

    dim3 g1(HALF / 256, nchunks);
    hipLaunchKernelGGL(vq_partial_kernel, g1, dim3(256), 0, stream,
                       z, emb, pval, pidx, codesPerChunk);
    hipLaunchKernelGGL(vq_reduce_kernel, dim3(POS / 256), dim3(256), 0, stream,
                       pval, pidx, emb, zq, indOut, nchunks);
}

// Round 5
// 131.711 us; speedup vs baseline: 1.6514x; 1.0937x over previous
//
#include <hip/hip_runtime.h>
#include <math.h>

// Problem constants: z [4,32,32,32] f32, embedding [32768,32] f32.
constexpr int Bc   = 4;
constexpr int Dc   = 32;
constexpr int HWc  = 1024;            // 32*32
constexpr int NE   = 32768;
constexpr int POS  = Bc * HWc;        // 4096 positions
constexpr int HALF = POS / 2;         // 2048: thread t owns positions t, t+2048

constexpr int NCHUNK = 128;           // code chunks
constexpr int CPC    = NE / NCHUNK;   // 256 codes per chunk
constexpr int XCDS   = 8;
constexpr int CPX    = NCHUNK / XCDS; // 16 chunks pinned per XCD
constexpr int PGRPS  = HALF / 256;    // 8 position-groups

// Monotonic float->uint encoding; pack with ~idx so that among equal values
// the SMALLER index wins under atomicMax (== jnp.argmax first-index rule).
__device__ inline unsigned long long packVI(float v, int idx) {
    unsigned u = __float_as_uint(v);
    u = (u & 0x80000000u) ? ~u : (u | 0x80000000u);
    return ((unsigned long long)u << 32) | (unsigned)(~idx);
}

// Kernel 1: block = (chunk, posgroup). Stage the chunk's 256 codes (32 KB)
// into LDS once, then scan: 2 positions/thread (64 z-floats pinned in VGPRs),
// 2 codes/iter, operands via broadcast ds_read_b128 (wave-uniform address).
// XCD-affinity: blockIdx%8 selects the XCD-pinned chunk group, so each XCD's
// L2 only ever reads 16 chunks = 512 KB (round-4 fetched the full 4 MB x8).
// Result folded into a packed atomicMax -- no partials buffer, no reduce pass.
__global__ __launch_bounds__(256, 4) void vq_partial_kernel(
    const float* __restrict__ z, const float* __restrict__ emb,
    unsigned long long* __restrict__ best)
{
    __shared__ float elds[CPC * Dc];          // 32 KB -> 4 blocks/CU

    const int lin    = blockIdx.x;            // 0..1023, all resident at once
    const int xcd    = lin & 7;               // dispatch round-robins XCDs
    const int j      = lin >> 3;              // 0..127
    const int chunk  = xcd * CPX + (j & (CPX - 1));
    const int posgrp = j >> 4;                // 0..7

    // ---- stage chunk -> LDS (coalesced float4), one-time ----
    {
        const float4* s4 = reinterpret_cast<const float4*>(emb + (size_t)chunk * CPC * Dc);
        float4* l4 = reinterpret_cast<float4*>(elds);
#pragma unroll
        for (int r = 0; r < (CPC * Dc / 4) / 256; ++r)
            l4[r * 256 + threadIdx.x] = s4[r * 256 + threadIdx.x];
    }

    // ---- load this thread's two z vectors, pin in VGPRs ----
    const int t  = posgrp * 256 + threadIdx.x;  // 0..2047
    const int p0 = t, p1 = t + HALF;
    const int b0 = p0 >> 10, hw0 = p0 & (HWc - 1);
    const int b1 = p1 >> 10, hw1 = p1 & (HWc - 1);
    const float* zp0 = z + (size_t)b0 * Dc * HWc + hw0;
    const float* zp1 = z + (size_t)b1 * Dc * HWc + hw1;

    float za[Dc], zb[Dc];
#pragma unroll
    for (int d = 0; d < Dc; ++d) {
        za[d] = zp0[(size_t)d * HWc];
        zb[d] = zp1[(size_t)d * HWc];
    }
#pragma unroll
    for (int d = 0; d < Dc; ++d) asm volatile("" : "+v"(za[d]), "+v"(zb[d]));

    __syncthreads();

    // ---- scan 256 codes from LDS: 2 codes/iter, 4 independent FMA chains ----
    const int c0 = chunk * CPC;
    float best0 = -INFINITY, best1 = -INFINITY;
    int   bi0 = c0, bi1 = c0;

    const float4* e4 = reinterpret_cast<const float4*>(elds);
#pragma unroll 1
    for (int cc = 0; cc < CPC; cc += 2) {
        const float4* p = e4 + cc * 8;      // code cc (8 float4), cc+1 follows
        float aC0P0 = 0.f, aC0P1 = 0.f, aC1P0 = 0.f, aC1P1 = 0.f;
#pragma unroll
        for (int q = 0; q < 8; ++q) {
            const float4 ea = p[q];         // code cc,   k = 4q..4q+3
            const float4 eb = p[8 + q];     // code cc+1, k = 4q..4q+3
            aC0P0 = fmaf(za[4*q+0], ea.x, aC0P0);
            aC0P1 = fmaf(zb[4*q+0], ea.x, aC0P1);
            aC1P0 = fmaf(za[4*q+0], eb.x, aC1P0);
            aC1P1 = fmaf(zb[4*q+0], eb.x, aC1P1);
            aC0P0 = fmaf(za[4*q+1], ea.y, aC0P0);
            aC0P1 = fmaf(zb[4*q+1], ea.y, aC0P1);
            aC1P0 = fmaf(za[4*q+1], eb.y, aC1P0);
            aC1P1 = fmaf(zb[4*q+1], eb.y, aC1P1);
            aC0P0 = fmaf(za[4*q+2], ea.z, aC0P0);
            aC0P1 = fmaf(zb[4*q+2], ea.z, aC0P1);
            aC1P0 = fmaf(za[4*q+2], eb.z, aC1P0);
            aC1P1 = fmaf(zb[4*q+2], eb.z, aC1P1);
            aC0P0 = fmaf(za[4*q+3], ea.w, aC0P0);
            aC0P1 = fmaf(zb[4*q+3], ea.w, aC0P1);
            aC1P0 = fmaf(za[4*q+3], eb.w, aC1P0);
            aC1P1 = fmaf(zb[4*q+3], eb.w, aC1P1);
        }
        const int c = c0 + cc;
        // strict '>' in ascending code order == first-index tie-break
        if (aC0P0 > best0) { best0 = aC0P0; bi0 = c; }
        if (aC1P0 > best0) { best0 = aC1P0; bi0 = c + 1; }
        if (aC0P1 > best1) { best1 = aC0P1; bi1 = c; }
        if (aC1P1 > best1) { best1 = aC1P1; bi1 = c + 1; }
    }

    atomicMax(best + p0, packVI(best0, bi0));
    atomicMax(best + p1, packVI(best1, bi1));
}

// Kernel 2: decode winner, gather embedding row (float4), write z_q [b,d,h,w]
// (consecutive threads -> consecutive hw -> coalesced per d), index as float.
__global__ __launch_bounds__(256) void vq_finish_kernel(
    const unsigned long long* __restrict__ best, const float* __restrict__ emb,
    float* __restrict__ zq, float* __restrict__ indOut)
{
    const int p = blockIdx.x * 256 + threadIdx.x;
    const unsigned long long pk = best[p];
    const int idx = (int)(~(unsigned)pk);     // low 32 bits stored as ~idx

    const float4* e = reinterpret_cast<const float4*>(emb + (size_t)idx * Dc);
    const int b  = p >> 10;
    const int hw = p & (HWc - 1);
    float* o = zq + (size_t)b * Dc * HWc + hw;
#pragma unroll
    for (int q = 0; q < 8; ++q) {
        const float4 v = e[q];
        o[(size_t)(4*q+0) * HWc] = v.x;
        o[(size_t)(4*q+1) * HWc] = v.y;
        o[(size_t)(4*q+2) * HWc] = v.z;
        o[(size_t)(4*q+3) * HWc] = v.w;
    }
    indOut[p] = (float)idx;                   // <= 32767: exact in fp32
}

extern "C" void kernel_launch(void* const* d_in, const int* in_sizes, int n_in,
                              void* d_out, int out_size, void* d_ws, size_t ws_size,
                              hipStream_t stream)
{
    const float* z   = (const float*)d_in[0];
    const float* emb = (const float*)d_in[1];

    float* out    = (float*)d_out;
    float* zq     = out;                         // 131072 floats
    float* indOut = out + (size_t)Bc * Dc * HWc; // 4096 index values (as f32)

    unsigned long long* best = (unsigned long long*)d_ws;   // 4096 x 8 B

    // encoded 0 == minimum of the monotonic ordering -> any real value wins
    hipMemsetAsync(best, 0, (size_t)POS * sizeof(unsigned long long), stream);

    hipLaunchKernelGGL(vq_partial_kernel, dim3(NCHUNK * PGRPS), dim3(256), 0,
                       stream, z, emb, best);
    hipLaunchKernelGGL(vq_finish_kernel, dim3(POS / 256), dim3(256), 0,
                       stream, best, emb, zq, indOut);
}

// Round 6
// 109.660 us; speedup vs baseline: 1.9835x; 1.2011x over previous
//
#include <hip/hip_runtime.h>
#include <math.h>

// Problem constants: z [4,32,32,32] f32, embedding [32768,32] f32.
constexpr int Bc   = 4;
constexpr int Dc   = 32;
constexpr int HWc  = 1024;            // 32*32
constexpr int NE   = 32768;
constexpr int POS  = Bc * HWc;        // 4096 positions
constexpr int HALF = POS / 2;         // 2048: thread t owns positions t, t+2048

constexpr int NCHUNK = 128;           // code chunks
constexpr int CPC    = NE / NCHUNK;   // 256 codes per chunk
constexpr int XCDS   = 8;
constexpr int CPX    = NCHUNK / XCDS; // 16 chunks pinned per XCD
constexpr int PGRPS  = HALF / 256;    // 8 position-groups

typedef float f32x16 __attribute__((ext_vector_type(16)));

// Monotonic float->uint encoding; pack with ~idx so that among equal values
// the SMALLER index wins under atomicMax (== jnp.argmax first-index rule).
__device__ inline unsigned long long packVI(float v, int idx) {
    unsigned u = __float_as_uint(v);
    u = (u & 0x80000000u) ? ~u : (u | 0x80000000u);
    return ((unsigned long long)u << 32) | (unsigned)(~idx);
}

// Kernel 1: block = (xcd-pinned chunk, posgroup). Embedding operands are
// wave-uniform -> fetched with inline-asm s_load_dwordx16 into SGPRs through
// the SCALAR pipe: no VALU issue slots, no VGPR pressure, no DS pipe (round 5
// paid 192 VGPRs + the LDS read pipe for the same broadcast). The
// s_waitcnt carries "+s" ties on the buffers so FMAs can't be hoisted above
// it. 2 codes/iter x 2 positions/thread = 4 independent FMA chains, 128 FMA
// per 140 issued wave-instructions. XCD-pinned chunks keep scalar loads
// L2-resident (512 KB/XCD slice).
__global__ __launch_bounds__(256, 4) void vq_partial_kernel(
    const float* __restrict__ z, const float* __restrict__ emb,
    unsigned long long* __restrict__ best)
{
    const int lin    = blockIdx.x;            // 0..1023, all resident at once
    const int xcd    = lin & 7;               // dispatch round-robins XCDs
    const int j      = lin >> 3;              // 0..127
    const int chunk  = xcd * CPX + (j & (CPX - 1));
    const int posgrp = j >> 4;                // 0..7

    // ---- this thread's two z vectors, pinned in VGPRs ----
    const int t  = posgrp * 256 + threadIdx.x;  // 0..2047
    const int p0 = t, p1 = t + HALF;
    const int b0 = p0 >> 10, hw0 = p0 & (HWc - 1);
    const int b1 = p1 >> 10, hw1 = p1 & (HWc - 1);
    const float* zp0 = z + (size_t)b0 * Dc * HWc + hw0;
    const float* zp1 = z + (size_t)b1 * Dc * HWc + hw1;

    float za[Dc], zb[Dc];
#pragma unroll
    for (int d = 0; d < Dc; ++d) {
        za[d] = zp0[(size_t)d * HWc];
        zb[d] = zp1[(size_t)d * HWc];
    }
#pragma unroll
    for (int d = 0; d < Dc; ++d) asm volatile("" : "+v"(za[d]), "+v"(zb[d]));

    // ---- scan this chunk's 256 codes via scalar loads ----
    const float* e  = emb + (size_t)chunk * CPC * Dc;   // wave-uniform
    const int    c0 = chunk * CPC;
    float v0 = -INFINITY, v1 = -INFINITY;
    int   i0 = c0, i1 = c0;

#pragma unroll 1
    for (int cc = 0; cc < CPC; cc += 2) {
        f32x16 eA, eB, eC, eD;   // code cc = eA:eB, code cc+1 = eC:eD
        asm volatile("s_load_dwordx16 %0, %1, 0x0"  : "=s"(eA) : "s"(e));
        asm volatile("s_load_dwordx16 %0, %1, 0x40" : "=s"(eB) : "s"(e));
        asm volatile("s_load_dwordx16 %0, %1, 0x80" : "=s"(eC) : "s"(e));
        asm volatile("s_load_dwordx16 %0, %1, 0xc0" : "=s"(eD) : "s"(e));
        // "+s" ties make every consumer data-dependent on the waitcnt
        asm volatile("s_waitcnt lgkmcnt(0)"
                     : "+s"(eA), "+s"(eB), "+s"(eC), "+s"(eD));

        float aC0P0 = 0.f, aC0P1 = 0.f, aC1P0 = 0.f, aC1P1 = 0.f;
#pragma unroll
        for (int k = 0; k < 16; ++k) {
            aC0P0 = fmaf(za[k],      eA[k], aC0P0);
            aC0P1 = fmaf(zb[k],      eA[k], aC0P1);
            aC1P0 = fmaf(za[k],      eC[k], aC1P0);
            aC1P1 = fmaf(zb[k],      eC[k], aC1P1);
            aC0P0 = fmaf(za[16 + k], eB[k], aC0P0);
            aC0P1 = fmaf(zb[16 + k], eB[k], aC0P1);
            aC1P0 = fmaf(za[16 + k], eD[k], aC1P0);
            aC1P1 = fmaf(zb[16 + k], eD[k], aC1P1);
        }

        const int c = c0 + cc;
        // strict '>' in ascending code order == first-index tie-break
        if (aC0P0 > v0) { v0 = aC0P0; i0 = c; }
        if (aC1P0 > v0) { v0 = aC1P0; i0 = c + 1; }
        if (aC0P1 > v1) { v1 = aC0P1; i1 = c; }
        if (aC1P1 > v1) { v1 = aC1P1; i1 = c + 1; }

        e += 2 * Dc;
    }

    atomicMax(best + p0, packVI(v0, i0));
    atomicMax(best + p1, packVI(v1, i1));
}

// Kernel 2: decode winner, gather embedding row (float4), write z_q [b,d,h,w]
// (consecutive threads -> consecutive hw -> coalesced per d), index as float.
__global__ __launch_bounds__(256) void vq_finish_kernel(
    const unsigned long long* __restrict__ best, const float* __restrict__ emb,
    float* __restrict__ zq, float* __restrict__ indOut)
{
    const int p = blockIdx.x * 256 + threadIdx.x;
    const unsigned long long pk = best[p];
    const int idx = (int)(~(unsigned)pk);     // low 32 bits stored as ~idx

    const float4* e = reinterpret_cast<const float4*>(emb + (size_t)idx * Dc);
    const int b  = p >> 10;
    const int hw = p & (HWc - 1);
    float* o = zq + (size_t)b * Dc * HWc + hw;
#pragma unroll
    for (int q = 0; q < 8; ++q) {
        const float4 v = e[q];
        o[(size_t)(4*q+0) * HWc] = v.x;
        o[(size_t)(4*q+1) * HWc] = v.y;
        o[(size_t)(4*q+2) * HWc] = v.z;
        o[(size_t)(4*q+3) * HWc] = v.w;
    }
    indOut[p] = (float)idx;                   // <= 32767: exact in fp32
}

extern "C" void kernel_launch(void* const* d_in, const int* in_sizes, int n_in,
                              void* d_out, int out_size, void* d_ws, size_t ws_size,
                              hipStream_t stream)
{
    const float* z   = (const float*)d_in[0];
    const float* emb = (const float*)d_in[1];

    float* out    = (float*)d_out;
    float* zq     = out;                         // 131072 floats
    float* indOut = out + (size_t)Bc * Dc * HWc; // 4096 index values (as f32)

    unsigned long long* best = (unsigned long long*)d_ws;   // 4096 x 8 B

    // encoded 0 == minimum of the monotonic ordering -> any real value wins
    hipMemsetAsync(best, 0, (size_t)POS * sizeof(unsigned long long), stream);

    hipLaunchKernelGGL(vq_partial_kernel, dim3(NCHUNK * PGRPS), dim3(256), 0,
                       stream, z, emb, best);
    hipLaunchKernelGGL(vq_finish_kernel, dim3(POS / 256), dim3(256), 0,
                       stream, best, emb, zq, indOut);
}